// Round 3
// baseline (269.890 us; speedup 1.0000x reference)
//
#include <hip/hip_runtime.h>
#include <math.h>

// Problem constants
#define T_  204
#define I_  5
#define H_  24
#define L_  10
#define O_  612
#define Bsz 8192

typedef _Float16 half8 __attribute__((ext_vector_type(8)));
typedef _Float16 half2t __attribute__((ext_vector_type(2)));
typedef float    float4t __attribute__((ext_vector_type(4)));

union U16B { float4t f4; half8 h8; float f[4]; _Float16 h[8]; half2t h2[4]; };

__device__ __forceinline__ float fast_rcp(float x){ return __builtin_amdgcn_rcpf(x); }
__device__ __forceinline__ float fast_ex2(float x){ return __builtin_amdgcn_exp2f(x); }
__device__ __forceinline__ half2t pk2(float a, float b){
    return __builtin_bit_cast(half2t, __builtin_amdgcn_cvt_pkrtz(a, b));
}

#define MFMA16(a,b,c) __builtin_amdgcn_mfma_f32_16x16x32_f16((a),(b),(c),0,0,0)

#define L2E  1.44269504f
#define L2E2 2.88539008f

__device__ __forceinline__ float sigm2(float x){ return fast_rcp(1.f + fast_ex2(x * -L2E)); }
__device__ __forceinline__ float tanh2(float x){ return 2.f * fast_rcp(1.f + fast_ex2(x * -L2E2)) - 1.f; }

// Prepack fc0_w into per-timestep fp16 A-fragments (A[m=l][k=j], zeros elsewhere).
__global__ __launch_bounds__(64)
void pack_fc0(const float* __restrict__ fc0_w, float4t* __restrict__ dst)
{
    const int t = blockIdx.x, lane = threadIdx.x;
    const int m = lane & 15, q = lane >> 4;
    U16B v;
    #pragma unroll
    for (int i = 0; i < 8; ++i) {
        const int k = 8*q + i;
        float f = (m < L_ && k < H_) ? fc0_w[m*(T_*H_) + t*H_ + k] : 0.0f;
        v.h[i] = (_Float16)f;
    }
    dst[t*64 + lane] = v.f4;
}

// R14: R10-R13 data => wall = 204 x per-step SERIAL CHAIN (all WGs resident;
// wave count irrelevant). Chain was MFMA -> act -> pack -> SHUFFLE/LDS exchange
// -> B rebuild -> MFMA. This version deletes the exchange: 8 gate tiles of 3
// units each (A rows 12-15 zero) so lane (m,q<3) owns units 8q+T, T=0..7 ==
// exactly its own 8 B-slots. h never crosses lanes; B rebuild = 4 pk2 from own
// registers. Cost: +2 MFMAs and +2 units of act issue (off-chain). Numerics
// bitwise identical to the 6-tile baseline (same k-sums, relocated tiles).
#define LSTM_STEP(tcur, xC, facur)                                              \
  {                                                                             \
    float4t D0 = MFMA16(Ag[0], B.h8, zf4);                                      \
    float4t D1 = MFMA16(Ag[1], B.h8, zf4);                                      \
    float4t D2 = MFMA16(Ag[2], B.h8, zf4);                                      \
    float4t D3 = MFMA16(Ag[3], B.h8, zf4);                                      \
    float4t D4 = MFMA16(Ag[4], B.h8, zf4);                                      \
    float4t D5 = MFMA16(Ag[5], B.h8, zf4);                                      \
    float4t D6 = MFMA16(Ag[6], B.h8, zf4);                                      \
    float4t D7 = MFMA16(Ag[7], B.h8, zf4);                                      \
    if (q < 3) {                                                                \
      float4t D[8] = {D0, D1, D2, D3, D4, D5, D6, D7};                          \
      float hh[8];                                                              \
      _Pragma("unroll")                                                         \
      for (int T8 = 0; T8 < 8; ++T8) {                                          \
        const float si = sigm2(D[T8][0]);                                       \
        const float sf = sigm2(D[T8][1]);                                       \
        const float tg = tanh2(D[T8][2]);                                       \
        const float so = sigm2(D[T8][3]);                                       \
        c_[T8] = fmaf(sf, c_[T8], si * tg);                                     \
        hh[T8] = so * tanh2(c_[T8]);                                            \
      }                                                                         \
      B.h2[0] = pk2(hh[0], hh[1]);                                              \
      B.h2[1] = pk2(hh[2], hh[3]);                                              \
      B.h2[2] = pk2(hh[4], hh[5]);                                              \
      B.h2[3] = pk2(hh[6], hh[7]);                                              \
    } else {                                                                    \
      B.h2[0] = pk2(xC[0], xC[1]);                                              \
      B.h2[1] = pk2(xC[2], xC[3]);                                              \
      B.h2[2] = pk2(xC[4], 1.0f);                                               \
      B.h2[3] = pk2(0.f, 0.f);                                                  \
    }                                                                           \
    U16B fF; fF.f4 = facur;                                                     \
    accF = MFMA16(fF.h8, B.h8, accF);                                           \
    {                                                                           \
      if (q == 3) {                                                             \
        const int tpx = ((tcur) + 3 < T_) ? (tcur) + 3 : (T_ - 1);              \
        _Pragma("unroll")                                                       \
        for (int i = 0; i < I_; ++i) xC[i] = xp[tpx * I_ + i];                   \
      }                                                                         \
      const int tfx = ((tcur) + 2 < T_) ? (tcur) + 2 : (T_ - 1);                \
      facur = fc0A[tfx * 64 + lane];                                            \
    }                                                                           \
  }

__global__ __launch_bounds__(64)
void lstm_mfma(const float* __restrict__ x,
               const float* __restrict__ W_ih,
               const float* __restrict__ W_hh,
               const float* __restrict__ b_ih,
               const float* __restrict__ b_hh,
               const float* __restrict__ fc0_b,
               const float* __restrict__ out_w,
               const float* __restrict__ out_b,
               const float4t* __restrict__ fc0A,   // prepacked in d_ws
               float* __restrict__ out)
{
    __shared__ __align__(16) _Float16 actL[16*24];  // epilogue staging only

    const int lane = threadIdx.x;
    const int m = lane & 15;        // batch col / A row-within-tile
    const int q = lane >> 4;        // quad (B k-slice owner)
    const int elem = blockIdx.x * 16 + m;

    const float4t zf4 = {0.f, 0.f, 0.f, 0.f};

    // ---- gate A-fragments: 8 tiles x 3 units ----
    // Tile T rows mm: mm<12 -> gate (mm&3) of unit 8*(mm>>2)+T; rows 12-15 zero.
    // => lane (m,q<3) D regs r = gate r of unit 8q+T: its OWN B-slot k=8q+T.
    half8 Ag[8];
    #pragma unroll
    for (int T8 = 0; T8 < 8; ++T8) {
        U16B tw;
        if (m < 12) {
            const int u = 8*(m >> 2) + T8;
            const int srow = (m & 3) * H_ + u;       // torch gate-major row
            float wv[8];
            if (q < 3) {
                const float4t* pw = (const float4t*)(W_hh + srow*H_ + 8*q);
                float4t wa = pw[0], wb = pw[1];
                #pragma unroll
                for (int i = 0; i < 4; ++i) { wv[i] = wa[i]; wv[4+i] = wb[i]; }
            } else {
                #pragma unroll
                for (int i = 0; i < 8; ++i) wv[i] = 0.f;
                #pragma unroll
                for (int i = 0; i < I_; ++i) wv[i] = W_ih[srow*I_ + i];
                wv[5] = b_ih[srow] + b_hh[srow];
            }
            #pragma unroll
            for (int i = 0; i < 8; ++i) tw.h[i] = (_Float16)wv[i];
        } else {
            tw.f4 = zf4;
        }
        Ag[T8] = tw.h8;
    }

    const float* xp = x + (size_t)elem * (T_*I_);

    // ---- initial B-frag [h=0 | x_0 | 1 | 0,0] ----
    U16B B;
    if (q == 3) {
        B.h2[0] = pk2(xp[0], xp[1]);
        B.h2[1] = pk2(xp[2], xp[3]);
        B.h2[2] = pk2(xp[4], 1.0f);
        B.h2[3] = pk2(0.f, 0.f);
    } else {
        B.f4 = zf4;
    }

    // ping-pong x prefetch (xE consumed at even t = holds x(t+1); xO at odd t),
    // reloaded at step bottom after consumption -> ~2-step vmem shadow.
    float xE[I_] = {0,0,0,0,0}, xO[I_] = {0,0,0,0,0};
    if (q == 3) {
        #pragma unroll
        for (int i = 0; i < I_; ++i) {
            xE[i] = xp[1*I_ + i];
            xO[i] = xp[2*I_ + i];
        }
    }

    float c_[8] = {0,0,0,0,0,0,0,0};
    float4t accF = zf4;
    float4t fa0 = fc0A[lane];          // fc0 frag for even t (starts t=0)
    float4t fa1 = fc0A[64 + lane];     // fc0 frag for odd t  (starts t=1)

    // ================= time loop (no barriers, no LDS, no cross-lane) ======
    #pragma unroll 1
    for (int t = 0; t < T_; t += 2) {
        LSTM_STEP(t,     xE, fa0)
        LSTM_STEP(t + 1, xO, fa1)
    }

    // ================= epilogue (validated R7/R8) =================
    float av[4];
    #pragma unroll
    for (int r = 0; r < 4; ++r) {
        const int l = 4*q + r;
        const float fb = (l < L_) ? fc0_b[l] : 0.f;
        const float v = accF[r] + fb;
        av[r] = (l < L_) ? fmaxf(v, 0.f) : 0.f;
    }
    *(half2t*)(&actL[m*24 + 4*q])     = pk2(av[0], av[1]);
    *(half2t*)(&actL[m*24 + 4*q + 2]) = pk2(av[2], av[3]);
    __builtin_amdgcn_wave_barrier();

    U16B Ba;
    if (q < 2) Ba.f4 = *(const float4t*)(&actL[m*24 + q*8]);
    else       Ba.f4 = zf4;            // k>=16 unused (out_w A-frag zero there)

    for (int Tt = 0; Tt < 39; ++Tt) {
        const int row = 16*Tt + m;
        float w0=0.f,w1=0.f,w2=0.f,w3=0.f,w4=0.f,w5=0.f,w6=0.f,w7=0.f;
        if (row < O_ && q < 2) {
            const float2* p2 = (const float2*)(out_w + row*L_);
            if (q == 0) {
                float2 a = p2[0], b = p2[1], cc = p2[2], dd = p2[3];
                w0=a.x; w1=a.y; w2=b.x; w3=b.y; w4=cc.x; w5=cc.y; w6=dd.x; w7=dd.y;
            } else {
                float2 a = p2[4];
                w0=a.x; w1=a.y;
            }
        }
        U16B Aw;
        Aw.h2[0] = pk2(w0,w1); Aw.h2[1] = pk2(w2,w3);
        Aw.h2[2] = pk2(w4,w5); Aw.h2[3] = pk2(w6,w7);

        float4t dd = MFMA16(Aw.h8, Ba.h8, zf4);

        const int ob = 16*Tt + 4*q;
        if (ob < O_) {
            const float4t bias = *(const float4t*)(out_b + ob);
            #pragma unroll
            for (int r = 0; r < 4; ++r) dd[r] += bias[r];
            *(float4t*)(out + (size_t)elem*O_ + ob) = dd;
        }
    }
}

extern "C" void kernel_launch(void* const* d_in, const int* in_sizes, int n_in,
                              void* d_out, int out_size, void* d_ws, size_t ws_size,
                              hipStream_t stream)
{
    const float* x     = (const float*)d_in[0];
    const float* W_ih  = (const float*)d_in[1];
    const float* W_hh  = (const float*)d_in[2];
    const float* b_ih  = (const float*)d_in[3];
    const float* b_hh  = (const float*)d_in[4];
    const float* fc0_w = (const float*)d_in[5];
    const float* fc0_b = (const float*)d_in[6];
    const float* out_w = (const float*)d_in[7];
    const float* out_b = (const float*)d_in[8];
    float* out = (float*)d_out;
    (void)ws_size;

    pack_fc0<<<dim3(T_), dim3(64), 0, stream>>>(fc0_w, (float4t*)d_ws);
    lstm_mfma<<<dim3(Bsz/16), dim3(64), 0, stream>>>(
        x, W_ih, W_hh, b_ih, b_hh, fc0_b, out_w, out_b,
        (const float4t*)d_ws, out);
}

// Round 4
// 218.446 us; speedup vs baseline: 1.2355x; 1.2355x over previous
//
#include <hip/hip_runtime.h>
#include <math.h>

// Problem constants
#define T_  204
#define I_  5
#define H_  24
#define L_  10
#define O_  612
#define Bsz 8192

typedef _Float16 half8 __attribute__((ext_vector_type(8)));
typedef _Float16 half2t __attribute__((ext_vector_type(2)));
typedef float    float4t __attribute__((ext_vector_type(4)));

union U16B { float4t f4; half8 h8; float f[4]; _Float16 h[8]; half2t h2[4]; };

__device__ __forceinline__ float fast_rcp(float x){ return __builtin_amdgcn_rcpf(x); }
__device__ __forceinline__ float fast_ex2(float x){ return __builtin_amdgcn_exp2f(x); }
__device__ __forceinline__ half2t pk2(float a, float b){
    return __builtin_bit_cast(half2t, __builtin_amdgcn_cvt_pkrtz(a, b));
}

#define MFMA16(a,b,c) __builtin_amdgcn_mfma_f32_16x16x32_f16((a),(b),(c),0,0,0)

#define L2E  1.44269504f
#define L2E2 2.88539008f

// Unit owned by lane-quad q, tile T (q<3: 8q+T; q==3: overflow units 6,7,14,15,22,23)
__device__ __forceinline__ int unit_of(int q, int T) {
    return (q < 3) ? (8*q + T) : (8*(T >> 1) + 6 + (T & 1));
}

// Prepack fc0_w into per-timestep fp16 A-fragments (A[m=l][k=j], zeros elsewhere).
__global__ __launch_bounds__(64)
void pack_fc0(const float* __restrict__ fc0_w, float4t* __restrict__ dst)
{
    const int t = blockIdx.x, lane = threadIdx.x;
    const int m = lane & 15, q = lane >> 4;
    U16B v;
    #pragma unroll
    for (int i = 0; i < 8; ++i) {
        const int k = 8*q + i;
        float f = (m < L_ && k < H_) ? fc0_w[m*(T_*H_) + t*H_ + k] : 0.0f;
        v.h[i] = (_Float16)f;
    }
    dst[t*64 + lane] = v.f4;
}

// R15: R11-R14 scaling data fit wall = ~29cy x per-lane TRANS-op count (R11
// 60->1740cy, R14 80->2320, R12 120->~3500, R13 30+sync). The kernel is bound
// by the transcendental pipe / serial exp->rcp pairs; MFMA count, exchange
// style, wave count are all second-order. So: keep the 148us R11 structure
// EXACTLY and cut trans 10->7 per unit-update via fused denominators:
//   c' = [c*D2*D3 + D1*(e2g-1)] * rcp(D1*D2*D3), D1=1+e^-f,D2=1+e^-i,D3=e2g+1
//   h  = copysign((1-es)*rcp((1+e^-o)(1+es)), c'), es=e^{-2|c'|} (no overflow)
// 5 exp + 2 rcp instead of 5 exp + 5 rcp. Units phase-interleaved so their
// chains overlap under in-order issue.
__global__ __launch_bounds__(64)
void lstm_mfma(const float* __restrict__ x,
               const float* __restrict__ W_ih,
               const float* __restrict__ W_hh,
               const float* __restrict__ b_ih,
               const float* __restrict__ b_hh,
               const float* __restrict__ fc0_b,
               const float* __restrict__ out_w,
               const float* __restrict__ out_b,
               const float4t* __restrict__ fc0A,   // prepacked in d_ws
               float* __restrict__ out)
{
    __shared__ __align__(16) _Float16 actL[16*24];  // epilogue staging only

    const int lane = threadIdx.x;
    const int m = lane & 15;        // element col / A row-within-tile
    const int q = lane >> 4;        // quad
    const int elem = blockIdx.x * 16 + m;

    const float4t zf4 = {0.f, 0.f, 0.f, 0.f};

    // ---- gate A-fragments ----
    half8 Ag[6];
    #pragma unroll
    for (int T6 = 0; T6 < 6; ++T6) {
        const int u = unit_of(m >> 2, T6);
        const int srow = (m & 3) * H_ + u;       // torch gate-major row
        float wv[8];
        if (q < 3) {
            const float4t* pw = (const float4t*)(W_hh + srow*H_ + 8*q);
            float4t wa = pw[0], wb = pw[1];
            #pragma unroll
            for (int i = 0; i < 4; ++i) { wv[i] = wa[i]; wv[4+i] = wb[i]; }
        } else {
            #pragma unroll
            for (int i = 0; i < 8; ++i) wv[i] = 0.f;
            #pragma unroll
            for (int i = 0; i < I_; ++i) wv[i] = W_ih[srow*I_ + i];
            wv[5] = b_ih[srow] + b_hh[srow];
        }
        U16B tw;
        #pragma unroll
        for (int i = 0; i < 8; ++i) tw.h[i] = (_Float16)wv[i];
        Ag[T6] = tw.h8;
    }

    const float* xp = x + (size_t)elem * (T_*I_);

    // ---- initial B-frag [h=0 | x_0 | 1 | 0,0]; x prefetch ring (depth 2) ----
    U16B B;
    if (q == 3) {
        B.h2[0] = pk2(xp[0], xp[1]);
        B.h2[1] = pk2(xp[2], xp[3]);
        B.h2[2] = pk2(xp[4], 1.0f);
        B.h2[3] = pk2(0.f, 0.f);
    } else {
        B.f4 = zf4;
    }
    float xC[I_] = {0,0,0,0,0};              // x(t+1), consumed at iter bottom
    if (q == 3) {
        #pragma unroll
        for (int i = 0; i < I_; ++i) xC[i] = xp[I_ + i];
    }

    float c_[6] = {0,0,0,0,0,0};
    float4t accF = zf4;
    float4t fa = fc0A[lane];                 // fc0 frag for t=0

    // ================= time loop (no barriers, no LDS) =================
    for (int t = 0; t < T_; ++t) {
        // prefetches: x(t+2) [~2 iters ahead, covers HBM ~900cyc], fc0 frag t+1
        const int tn = (t + 1 < T_) ? t + 1 : t;
        const float4t fan = fc0A[tn*64 + lane];
        float xN[I_] = {0,0,0,0,0};
        if (q == 3) {
            const int tp2 = (t + 2 < T_) ? t + 2 : T_ - 1;
            const float* xq = xp + tp2*I_;
            #pragma unroll
            for (int i = 0; i < I_; ++i) xN[i] = xq[i];
        }

        // 6 gate MFMAs
        float4t D0 = MFMA16(Ag[0], B.h8, zf4);
        float4t D1 = MFMA16(Ag[1], B.h8, zf4);
        float4t D2 = MFMA16(Ag[2], B.h8, zf4);
        float4t D3 = MFMA16(Ag[3], B.h8, zf4);
        float4t D4 = MFMA16(Ag[4], B.h8, zf4);
        float4t D5 = MFMA16(Ag[5], B.h8, zf4);

        // fused-denominator cell update, phase-interleaved across 6 units
        float hh[6];
        {
            float4t D[6] = {D0, D1, D2, D3, D4, D5};
            float ei[6], ef[6], eg[6], eo[6];
            #pragma unroll
            for (int u = 0; u < 6; ++u) {
                ei[u] = fast_ex2(D[u][0] * -L2E);    // e^{-i}
                ef[u] = fast_ex2(D[u][1] * -L2E);    // e^{-f}
                eg[u] = fast_ex2(D[u][2] *  L2E2);   // e^{+2g}
                eo[u] = fast_ex2(D[u][3] * -L2E);    // e^{-o}
            }
            float R1[6], nm[6];
            #pragma unroll
            for (int u = 0; u < 6; ++u) {
                const float Dn1 = 1.f + ef[u];       // 1/sigm(f)
                const float Dn2 = 1.f + ei[u];       // 1/sigm(i)
                const float Dn3 = eg[u] + 1.f;       // tanh(g) denom
                const float G   = eg[u] - 1.f;       // tanh(g) numer
                const float P   = Dn2 * Dn3;
                R1[u] = fast_rcp(Dn1 * P);
                nm[u] = fmaf(c_[u], P, Dn1 * G);
            }
            float es[6];
            #pragma unroll
            for (int u = 0; u < 6; ++u) {
                c_[u] = nm[u] * R1[u];
                es[u] = fast_ex2(__builtin_fabsf(c_[u]) * -L2E2);  // e^{-2|c'|}
            }
            #pragma unroll
            for (int u = 0; u < 6; ++u) {
                const float R2 = fast_rcp((1.f + eo[u]) * (1.f + es[u]));
                hh[u] = __builtin_copysignf((1.f - es[u]) * R2, c_[u]);
            }
        }

        // pack own h pairs; q3's pairs are the overflow units consumers need:
        // P0 = (u6,u7) -> q0's k-slots 6,7; P1 = (u14,u15) -> q1; P2 = (u22,u23) -> q2
        const float P0 = __builtin_bit_cast(float, pk2(hh[0], hh[1]));
        const float P1 = __builtin_bit_cast(float, pk2(hh[2], hh[3]));
        const float P2 = __builtin_bit_cast(float, pk2(hh[4], hh[5]));

        // fetch overflow pair from lane (m, q=3) = lane 48+m (3 bpermutes, no barrier)
        const int src = 48 + m;
        const float r0 = __shfl(P0, src, 64);
        const float r1 = __shfl(P1, src, 64);
        const float r2 = __shfl(P2, src, 64);
        const float rcv = (q == 0) ? r0 : ((q == 1) ? r1 : r2);

        // rebuild B-frag
        if (q < 3) {
            B.h2[0] = __builtin_bit_cast(half2t, P0);   // units 8q+0,1
            B.h2[1] = __builtin_bit_cast(half2t, P1);   // units 8q+2,3
            B.h2[2] = __builtin_bit_cast(half2t, P2);   // units 8q+4,5
            B.h2[3] = __builtin_bit_cast(half2t, rcv);  // units 8q+6,7 (from q3)
        } else {
            B.h2[0] = pk2(xC[0], xC[1]);
            B.h2[1] = pk2(xC[2], xC[3]);
            B.h2[2] = pk2(xC[4], 1.0f);
            B.h2[3] = pk2(0.f, 0.f);
        }

        // fc0 accumulation with h_t (fc0A rows k>=24 are zero)
        U16B fF; fF.f4 = fa;
        accF = MFMA16(fF.h8, B.h8, accF);

        fa = fan;
        #pragma unroll
        for (int i = 0; i < I_; ++i) xC[i] = xN[i];
    }

    // ================= epilogue (validated R7/R8) =================
    float av[4];
    #pragma unroll
    for (int r = 0; r < 4; ++r) {
        const int l = 4*q + r;
        const float fb = (l < L_) ? fc0_b[l] : 0.f;
        const float v = accF[r] + fb;
        av[r] = (l < L_) ? fmaxf(v, 0.f) : 0.f;
    }
    *(half2t*)(&actL[m*24 + 4*q])     = pk2(av[0], av[1]);
    *(half2t*)(&actL[m*24 + 4*q + 2]) = pk2(av[2], av[3]);
    __builtin_amdgcn_wave_barrier();

    U16B Ba;
    if (q < 2) Ba.f4 = *(const float4t*)(&actL[m*24 + q*8]);
    else       Ba.f4 = zf4;            // k>=16 unused (out_w A-frag zero there)

    for (int Tt = 0; Tt < 39; ++Tt) {
        const int row = 16*Tt + m;
        float w0=0.f,w1=0.f,w2=0.f,w3=0.f,w4=0.f,w5=0.f,w6=0.f,w7=0.f;
        if (row < O_ && q < 2) {
            const float2* p2 = (const float2*)(out_w + row*L_);
            if (q == 0) {
                float2 a = p2[0], b = p2[1], cc = p2[2], dd = p2[3];
                w0=a.x; w1=a.y; w2=b.x; w3=b.y; w4=cc.x; w5=cc.y; w6=dd.x; w7=dd.y;
            } else {
                float2 a = p2[4];
                w0=a.x; w1=a.y;
            }
        }
        U16B Aw;
        Aw.h2[0] = pk2(w0,w1); Aw.h2[1] = pk2(w2,w3);
        Aw.h2[2] = pk2(w4,w5); Aw.h2[3] = pk2(w6,w7);

        float4t dd = MFMA16(Aw.h8, Ba.h8, zf4);

        const int ob = 16*Tt + 4*q;
        if (ob < O_) {
            const float4t bias = *(const float4t*)(out_b + ob);
            #pragma unroll
            for (int r = 0; r < 4; ++r) dd[r] += bias[r];
            *(float4t*)(out + (size_t)elem*O_ + ob) = dd;
        }
    }
}

extern "C" void kernel_launch(void* const* d_in, const int* in_sizes, int n_in,
                              void* d_out, int out_size, void* d_ws, size_t ws_size,
                              hipStream_t stream)
{
    const float* x     = (const float*)d_in[0];
    const float* W_ih  = (const float*)d_in[1];
    const float* W_hh  = (const float*)d_in[2];
    const float* b_ih  = (const float*)d_in[3];
    const float* b_hh  = (const float*)d_in[4];
    const float* fc0_w = (const float*)d_in[5];
    const float* fc0_b = (const float*)d_in[6];
    const float* out_w = (const float*)d_in[7];
    const float* out_b = (const float*)d_in[8];
    float* out = (float*)d_out;
    (void)ws_size;

    pack_fc0<<<dim3(T_), dim3(64), 0, stream>>>(fc0_w, (float4t*)d_ws);
    lstm_mfma<<<dim3(Bsz/16), dim3(64), 0, stream>>>(
        x, W_ih, W_hh, b_ih, b_hh, fc0_b, out_w, out_b,
        (const float4t*)d_ws, out);
}